// Round 1
// baseline (263.819 us; speedup 1.0000x reference)
//
#include <hip/hip_runtime.h>
#include <math.h>

// GGNN message-passing GRU, N=2048, SD=32, MD=16, 10 steps.
// Strategy: block b owns nodes [4b, 4b+4) for the entire run. Per step-kernel:
//   phase 2: msg[j] += sum_i relu(ai[i,:] + aj[j,:] + J[i,j]*wJ)   (heavy)
//   phase 3: GRU update -> h_new (block-local)
//   phase 1': ai/aj for NEXT step from h_new (ai double-buffered across launches)
// Kernel boundaries provide the only needed global sync (ai is the only
// cross-block value). J is transposed once into ws so phase-2 i-streaming is
// coalesced. Workspace need: ~17.6 MB.

#define GN 2048
#define GSD 32
#define GMD 16
#define GSTEPS 10
#define NPB 4            // nodes (j columns) per block
#define NBLK (GN / NPB)  // 512 blocks
#define TI 256           // i-tile staged in LDS
#define BLK 256

// ---------------- J transpose (once) ----------------
__global__ __launch_bounds__(256)
void transpose_kernel(const float* __restrict__ J, float* __restrict__ Jt)
{
    __shared__ float tile[64][65];
    const int tx = threadIdx.x & 63;
    const int ty = threadIdx.x >> 6;
    const int bx = blockIdx.x, by = blockIdx.y;
#pragma unroll
    for (int r = ty; r < 64; r += 4)
        tile[r][tx] = J[(size_t)(by * 64 + r) * GN + bx * 64 + tx];
    __syncthreads();
#pragma unroll
    for (int r = ty; r < 64; r += 4)
        Jt[(size_t)(bx * 64 + r) * GN + by * 64 + tx] = tile[tx][r];
}

// ---------------- init: h=0, msg=0, ai0/aj0 from h=0 ----------------
__global__ __launch_bounds__(256)
void init_kernel(const float* __restrict__ b, const float* __restrict__ Wmsg,
                 const float* __restrict__ bmsg,
                 float* __restrict__ ai, float* __restrict__ aj,
                 float* __restrict__ h, float* __restrict__ msg)
{
    const int idx = blockIdx.x * 256 + threadIdx.x;   // grid covers GN*GSD
    if (idx < GN * GMD) {
        const int i = idx >> 4, m = idx & 15;
        const float bb = b[i];
        ai[idx] = fmaf(bb, Wmsg[m * 67 + 65], bmsg[m]);  // b*w_bi + b_msg
        aj[idx] = bb * Wmsg[m * 67 + 66];                // b*w_bj
        msg[idx] = 0.f;
    }
    h[idx] = 0.f;
}

// ---------------- one GGNN step ----------------
__global__ __launch_bounds__(BLK, 2)
void step_kernel(const float* __restrict__ Jt,
                 const float* __restrict__ ai_in,
                 float* __restrict__ ai_out,
                 float* __restrict__ aj,
                 float* __restrict__ h,
                 float* __restrict__ msg,
                 const float* __restrict__ b,
                 const float* __restrict__ Wmsg,
                 const float* __restrict__ bmsg,
                 const float* __restrict__ Wih,
                 const float* __restrict__ bih,
                 const float* __restrict__ bhh)
{
    __shared__ float sWih[96][49];                     // padded vs bank conflicts
    __shared__ float sWhi[GMD][GSD + 1];
    __shared__ float sWhj[GMD][GSD + 1];
    __shared__ __align__(16) float sJ[NPB][TI + 1];
    __shared__ __align__(16) float sAi[TI][GMD];
    __shared__ float sx[NPB][GSD + GMD];
    __shared__ float sg[NPB][3 * GSD];
    __shared__ float smsg[NPB][GMD];
    __shared__ __align__(16) float spart[16][NPB][GMD];
    __shared__ __align__(16) float swJ[GMD];
    __shared__ float swbi[GMD], swbj[GMD], sbm[GMD];
    __shared__ float sbih[3 * GSD], sbhh[3 * GSD];

    const int t = threadIdx.x;
    const int jb = blockIdx.x * NPB;

    // ---- stage weights + block-local state ----
    for (int idx = t; idx < 96 * 48; idx += BLK) sWih[idx / 48][idx % 48] = Wih[idx];
    for (int idx = t; idx < GMD * GSD; idx += BLK) {
        const int m = idx >> 5, k = idx & 31;
        sWhi[m][k] = Wmsg[m * 67 + k];
        sWhj[m][k] = Wmsg[m * 67 + GSD + k];
    }
    if (t < GMD) {
        swJ[t]  = Wmsg[t * 67 + 64];
        swbi[t] = Wmsg[t * 67 + 65];
        swbj[t] = Wmsg[t * 67 + 66];
        sbm[t]  = bmsg[t];
    }
    if (t < 96) { sbih[t] = bih[t]; sbhh[t] = bhh[t]; }
    if (t < NPB * GMD) smsg[t >> 4][t & 15] = msg[(jb + (t >> 4)) * GMD + (t & 15)];
    if (t < NPB * GSD) sx[t >> 5][t & 31] = h[(size_t)(jb + (t >> 5)) * GSD + (t & 31)];
    __syncthreads();

    // ---- phase 2: msg relu-sum ----
    // thread layout: mq = m-quad (4), jl = local j (4), sub = i-subchunk (16)
    const int mq  = t & 3;
    const int jl  = (t >> 2) & 3;
    const int sub = t >> 4;

    const float4 aj4 = *(const float4*)&aj[(size_t)(jb + jl) * GMD + mq * 4];
    const float4 wj4 = *(const float4*)&swJ[mq * 4];

    float4 acc = make_float4(0.f, 0.f, 0.f, 0.f);
    for (int tl = 0; tl < GN / TI; ++tl) {
        const int i0 = tl * TI;
        __syncthreads();  // previous tile fully consumed
        for (int idx = t; idx < NPB * TI; idx += BLK) {
            const int r = idx >> 8, c = idx & (TI - 1);
            sJ[r][c] = Jt[(size_t)(jb + r) * GN + i0 + c];
        }
        {
            const float4* __restrict__ src = (const float4*)(ai_in + (size_t)i0 * GMD);
            float4* dst = (float4*)&sAi[0][0];
            for (int idx = t; idx < TI * GMD / 4; idx += BLK) dst[idx] = src[idx];
        }
        __syncthreads();
#pragma unroll
        for (int ii = 0; ii < 16; ++ii) {
            const int i = sub * 16 + ii;
            const float Jv = sJ[jl][i];
            const float4 a4 = *(const float4*)&sAi[i][mq * 4];
            acc.x += fmaxf(fmaf(Jv, wj4.x, a4.x + aj4.x), 0.f);
            acc.y += fmaxf(fmaf(Jv, wj4.y, a4.y + aj4.y), 0.f);
            acc.z += fmaxf(fmaf(Jv, wj4.z, a4.z + aj4.z), 0.f);
            acc.w += fmaxf(fmaf(Jv, wj4.w, a4.w + aj4.w), 0.f);
        }
    }
    *(float4*)&spart[sub][jl][mq * 4] = acc;
    __syncthreads();

    // reduce the 16 i-subchunk partials, update msg (deterministic order)
    if (t < NPB * GMD) {
        const int jl2 = t >> 4, m2 = t & 15;
        float s = 0.f;
#pragma unroll
        for (int sb = 0; sb < 16; ++sb) s += spart[sb][jl2][m2];
        const float mnew = smsg[jl2][m2] + s;
        smsg[jl2][m2] = mnew;
        msg[(size_t)(jb + jl2) * GMD + m2] = mnew;
        sx[jl2][GSD + m2] = mnew;   // x = [h, msg_new]
    }
    __syncthreads();

    // ---- phase 3: g = W_ih @ x + b_ih ----
    for (int idx = t; idx < NPB * 96; idx += BLK) {
        const int node = idx / 96, r = idx - node * 96;
        float a = sbih[r];
#pragma unroll
        for (int c = 0; c < GSD + GMD; ++c) a = fmaf(sWih[r][c], sx[node][c], a);
        sg[node][r] = a;
    }
    __syncthreads();

    // GRU gates -> h_new
    if (t < NPB * GSD) {
        const int node = t >> 5, k = t & 31;
        const float gr = sg[node][k]           + sbhh[k];
        const float gz = sg[node][GSD + k]     + sbhh[GSD + k];
        const float gn = sg[node][2 * GSD + k];
        const float r_ = 1.f / (1.f + expf(-gr));
        const float z_ = 1.f / (1.f + expf(-gz));
        const float n_ = tanhf(fmaf(r_, sbhh[2 * GSD + k], gn));
        const float hn = (1.f - z_) * n_;
        sx[node][k] = hn;                                  // h_new for phase 1'
        h[(size_t)(jb + node) * GSD + k] = hn;
    }
    __syncthreads();

    // ---- phase 1': ai/aj for next step from h_new ----
    if (t < 2 * NPB * GMD) {
        const int which = t >> 6;
        const int node  = (t >> 4) & 3;
        const int m     = t & 15;
        const float bb = b[jb + node];
        if (which == 0) {
            float a = fmaf(bb, swbi[m], sbm[m]);
#pragma unroll
            for (int k = 0; k < GSD; ++k) a = fmaf(sWhi[m][k], sx[node][k], a);
            ai_out[(size_t)(jb + node) * GMD + m] = a;
        } else {
            float a = bb * swbj[m];
#pragma unroll
            for (int k = 0; k < GSD; ++k) a = fmaf(sWhj[m][k], sx[node][k], a);
            aj[(size_t)(jb + node) * GMD + m] = a;
        }
    }
}

// ---------------- readout + softmax ----------------
__global__ __launch_bounds__(1024)
void final_kernel(const float* __restrict__ h, const float* __restrict__ Wro,
                  const float* __restrict__ bro, float* __restrict__ out)
{
    __shared__ float slog[GN];
    __shared__ float sred[1024];
    __shared__ float swro[GSD];
    const int t = threadIdx.x;
    if (t < GSD) swro[t] = Wro[t];
    __syncthreads();
#pragma unroll
    for (int rr = 0; rr < 2; ++rr) {
        const int i = t + rr * 1024;
        float a = bro[0];
#pragma unroll
        for (int k = 0; k < GSD; ++k) a = fmaf(h[(size_t)i * GSD + k], swro[k], a);
        slog[i] = a;
    }
    __syncthreads();
    sred[t] = fmaxf(slog[t], slog[t + 1024]);
    __syncthreads();
    for (int s = 512; s > 0; s >>= 1) {
        if (t < s) sred[t] = fmaxf(sred[t], sred[t + s]);
        __syncthreads();
    }
    const float gmax = sred[0];
    __syncthreads();
    const float e0 = expf(slog[t] - gmax);
    const float e1 = expf(slog[t + 1024] - gmax);
    sred[t] = e0 + e1;
    __syncthreads();
    for (int s = 512; s > 0; s >>= 1) {
        if (t < s) sred[t] += sred[t + s];
        __syncthreads();
    }
    const float inv = 1.f / sred[0];
    out[t] = e0 * inv;
    out[t + 1024] = e1 * inv;
}

extern "C" void kernel_launch(void* const* d_in, const int* in_sizes, int n_in,
                              void* d_out, int out_size, void* d_ws, size_t ws_size,
                              hipStream_t stream)
{
    const float* J    = (const float*)d_in[0];
    const float* b    = (const float*)d_in[1];
    const float* Wmsg = (const float*)d_in[2];
    const float* bmsg = (const float*)d_in[3];
    const float* Wih  = (const float*)d_in[4];
    // d_in[5] = W_hh: unused by the reference math (only b_hh enters the gates)
    const float* bih  = (const float*)d_in[6];
    const float* bhh  = (const float*)d_in[7];
    const float* Wro  = (const float*)d_in[8];
    const float* bro  = (const float*)d_in[9];
    float* out = (float*)d_out;

    // workspace layout (floats); total ~17.6 MB
    float* ws   = (float*)d_ws;
    float* Jt   = ws;                           // N*N
    float* ai0  = Jt  + (size_t)GN * GN;        // N*MD
    float* ai1  = ai0 + (size_t)GN * GMD;       // N*MD  (double buffer)
    float* ajb  = ai1 + (size_t)GN * GMD;       // N*MD
    float* hbuf = ajb + (size_t)GN * GMD;       // N*SD
    float* msgb = hbuf + (size_t)GN * GSD;      // N*MD

    transpose_kernel<<<dim3(32, 32), 256, 0, stream>>>(J, Jt);
    init_kernel<<<GN * GSD / 256, 256, 0, stream>>>(b, Wmsg, bmsg, ai0, ajb, hbuf, msgb);

    float* ain = ai0;
    float* aout = ai1;
    for (int s = 0; s < GSTEPS; ++s) {
        step_kernel<<<NBLK, BLK, 0, stream>>>(Jt, ain, aout, ajb, hbuf, msgb,
                                              b, Wmsg, bmsg, Wih, bih, bhh);
        float* tmp = ain; ain = aout; aout = tmp;
    }
    final_kernel<<<1, 1024, 0, stream>>>(hbuf, Wro, bro, out);
}

// Round 2
// 221.837 us; speedup vs baseline: 1.1892x; 1.1892x over previous
//
#include <hip/hip_runtime.h>
#include <math.h>

// GGNN message-passing GRU, N=2048, SD=32, MD=16, 10 steps.
// Block b owns nodes [4b, 4b+4) for the whole run. Per step-kernel:
//   phase 2: msg[j] += sum_i relu(ai[i,:] + aj[j,:] + J[i,j]*wJ)   (heavy)
//   phase 3: GRU update -> h_new (block-local)
//   phase 1': ai/aj for NEXT step (ai kept TRANSPOSED [m][i], double-buffered)
// Main loop is LDS-free and barrier-free: thread (mq,isub) register-blocks
// all 4 j and its 4 m over a private 32-wide i-slice; J and aiT stream as
// contiguous per-thread float4 global loads (L2-resident).

#define GN 2048
#define GSD 32
#define GMD 16
#define GSTEPS 10
#define NPB 4            // nodes (j columns) per block
#define NBLK (GN / NPB)  // 512 blocks
#define BLK 256

// ---------------- J transpose (once) ----------------
__global__ __launch_bounds__(256)
void transpose_kernel(const float* __restrict__ J, float* __restrict__ Jt)
{
    __shared__ float tile[64][65];
    const int tx = threadIdx.x & 63;
    const int ty = threadIdx.x >> 6;
    const int bx = blockIdx.x, by = blockIdx.y;
#pragma unroll
    for (int r = ty; r < 64; r += 4)
        tile[r][tx] = J[(size_t)(by * 64 + r) * GN + bx * 64 + tx];
    __syncthreads();
#pragma unroll
    for (int r = ty; r < 64; r += 4)
        Jt[(size_t)(bx * 64 + r) * GN + by * 64 + tx] = tile[tx][r];
}

// ---------------- init: h=0, msg=0, aiT0/aj0 from h=0 ----------------
__global__ __launch_bounds__(256)
void init_kernel(const float* __restrict__ b, const float* __restrict__ Wmsg,
                 const float* __restrict__ bmsg,
                 float* __restrict__ aiT, float* __restrict__ aj,
                 float* __restrict__ h, float* __restrict__ msg)
{
    const int idx = blockIdx.x * 256 + threadIdx.x;   // grid covers GN*GSD
    if (idx < GN * GMD) {
        const int node = idx >> 4, m = idx & 15;
        const float bb = b[node];
        aiT[(size_t)m * GN + node] = fmaf(bb, Wmsg[m * 67 + 65], bmsg[m]);
        aj[idx] = bb * Wmsg[m * 67 + 66];
        msg[idx] = 0.f;
    }
    h[idx] = 0.f;
}

// ---------------- one GGNN step ----------------
__global__ __launch_bounds__(BLK, 2)
void step_kernel(const float* __restrict__ Jt,
                 const float* __restrict__ aiT_in,
                 float* __restrict__ aiT_out,
                 float* __restrict__ aj,
                 float* __restrict__ h,
                 float* __restrict__ msg,
                 const float* __restrict__ b,
                 const float* __restrict__ Wmsg,
                 const float* __restrict__ bmsg,
                 const float* __restrict__ Wih,
                 const float* __restrict__ bih,
                 const float* __restrict__ bhh)
{
    __shared__ float sWih[96][49];                 // padded vs bank conflicts
    __shared__ float sWhi[GMD][GSD + 1];
    __shared__ float sWhj[GMD][GSD + 1];
    __shared__ float sx[NPB][GSD + GMD];
    __shared__ float sg[NPB][3 * GSD];
    __shared__ __align__(16) float spart[4][4][NPB][4];  // [wave][mq][jl][mi]
    __shared__ float swbi[GMD], swbj[GMD], sbm[GMD];
    __shared__ float sbih[3 * GSD], sbhh[3 * GSD];

    const int t = threadIdx.x;
    const int jb = blockIdx.x * NPB;
    const int mq   = t & 3;        // m-quad: m = mq*4 + mi
    const int isub = t >> 2;       // 0..63, owns i in [isub*32, isub*32+32)

    // ---- stage weights + block-local state (visible after first barrier) ----
    for (int idx = t; idx < 96 * 48; idx += BLK) sWih[idx / 48][idx % 48] = Wih[idx];
    for (int idx = t; idx < GMD * GSD; idx += BLK) {
        const int m = idx >> 5, k = idx & 31;
        sWhi[m][k] = Wmsg[m * 67 + k];
        sWhj[m][k] = Wmsg[m * 67 + GSD + k];
    }
    if (t < GMD) { swbi[t] = Wmsg[t * 67 + 65]; swbj[t] = Wmsg[t * 67 + 66]; sbm[t] = bmsg[t]; }
    if (t < 96) { sbih[t] = bih[t]; sbhh[t] = bhh[t]; }
    if (t < NPB * GSD) sx[t >> 5][t & 31] = h[(size_t)(jb + (t >> 5)) * GSD + (t & 31)];

    // ---- phase 2: barrier-free, LDS-free relu-sum stream ----
    float wj[4];
#pragma unroll
    for (int mi = 0; mi < 4; ++mi) wj[mi] = Wmsg[(mq * 4 + mi) * 67 + 64];

    float ajv[NPB][4];
#pragma unroll
    for (int jl = 0; jl < NPB; ++jl) {
        const float4 a = *(const float4*)&aj[(size_t)(jb + jl) * GMD + mq * 4];
        ajv[jl][0] = a.x; ajv[jl][1] = a.y; ajv[jl][2] = a.z; ajv[jl][3] = a.w;
    }

    const int i0 = isub * 32;
    const float* __restrict__ Jr[NPB];
    const float* __restrict__ Ar[4];
#pragma unroll
    for (int jl = 0; jl < NPB; ++jl) Jr[jl] = Jt + (size_t)(jb + jl) * GN + i0;
#pragma unroll
    for (int mi = 0; mi < 4; ++mi) Ar[mi] = aiT_in + (size_t)(mq * 4 + mi) * GN + i0;

    float acc[NPB][4];
#pragma unroll
    for (int jl = 0; jl < NPB; ++jl)
#pragma unroll
        for (int mi = 0; mi < 4; ++mi) acc[jl][mi] = 0.f;

#pragma unroll 2
    for (int c = 0; c < 8; ++c) {
        const int ic = c * 4;
        float jv[NPB][4], av[4][4];
#pragma unroll
        for (int jl = 0; jl < NPB; ++jl) {
            const float4 v = *(const float4*)(Jr[jl] + ic);
            jv[jl][0] = v.x; jv[jl][1] = v.y; jv[jl][2] = v.z; jv[jl][3] = v.w;
        }
#pragma unroll
        for (int mi = 0; mi < 4; ++mi) {
            const float4 v = *(const float4*)(Ar[mi] + ic);
            av[mi][0] = v.x; av[mi][1] = v.y; av[mi][2] = v.z; av[mi][3] = v.w;
        }
#pragma unroll
        for (int q = 0; q < 4; ++q)
#pragma unroll
            for (int jl = 0; jl < NPB; ++jl)
#pragma unroll
                for (int mi = 0; mi < 4; ++mi)
                    acc[jl][mi] += fmaxf(fmaf(jv[jl][q], wj[mi], av[mi][q] + ajv[jl][mi]), 0.f);
    }

    // reduce over isub within each wave (lane = isub*4 + mq; isub bits are lane bits 2..5)
#pragma unroll
    for (int d = 4; d < 64; d <<= 1)
#pragma unroll
        for (int jl = 0; jl < NPB; ++jl)
#pragma unroll
            for (int mi = 0; mi < 4; ++mi)
                acc[jl][mi] += __shfl_xor(acc[jl][mi], d, 64);

    if ((t & 63) < 4) {  // one lane per (wave, mq)
        const int w = t >> 6;
#pragma unroll
        for (int jl = 0; jl < NPB; ++jl)
            *(float4*)&spart[w][mq][jl][0] =
                make_float4(acc[jl][0], acc[jl][1], acc[jl][2], acc[jl][3]);
    }
    __syncthreads();

    // combine 4 wave-partials, update msg (deterministic order)
    if (t < NPB * GMD) {
        const int jl = t >> 4, m = t & 15;
        float s = 0.f;
#pragma unroll
        for (int w = 0; w < 4; ++w) s += spart[w][m >> 2][jl][m & 3];
        const float mnew = msg[(size_t)(jb + jl) * GMD + m] + s;
        msg[(size_t)(jb + jl) * GMD + m] = mnew;
        sx[jl][GSD + m] = mnew;   // x = [h, msg_new]
    }
    __syncthreads();

    // ---- phase 3: g = W_ih @ x + b_ih ----
    for (int idx = t; idx < NPB * 96; idx += BLK) {
        const int node = idx / 96, r = idx - node * 96;
        float a = sbih[r];
#pragma unroll
        for (int c = 0; c < GSD + GMD; ++c) a = fmaf(sWih[r][c], sx[node][c], a);
        sg[node][r] = a;
    }
    __syncthreads();

    // GRU gates -> h_new
    if (t < NPB * GSD) {
        const int node = t >> 5, k = t & 31;
        const float gr = sg[node][k]           + sbhh[k];
        const float gz = sg[node][GSD + k]     + sbhh[GSD + k];
        const float gn = sg[node][2 * GSD + k];
        const float r_ = 1.f / (1.f + expf(-gr));
        const float z_ = 1.f / (1.f + expf(-gz));
        const float n_ = tanhf(fmaf(r_, sbhh[2 * GSD + k], gn));
        const float hn = (1.f - z_) * n_;
        sx[node][k] = hn;                                  // h_new for phase 1'
        h[(size_t)(jb + node) * GSD + k] = hn;
    }
    __syncthreads();

    // ---- phase 1': ai/aj for next step from h_new ----
    if (t < 2 * NPB * GMD) {
        const int which = t >> 6;
        const int node  = (t >> 4) & 3;
        const int m     = t & 15;
        const float bb = b[jb + node];
        if (which == 0) {
            float a = fmaf(bb, swbi[m], sbm[m]);
#pragma unroll
            for (int k = 0; k < GSD; ++k) a = fmaf(sWhi[m][k], sx[node][k], a);
            aiT_out[(size_t)m * GN + jb + node] = a;       // transposed store
        } else {
            float a = bb * swbj[m];
#pragma unroll
            for (int k = 0; k < GSD; ++k) a = fmaf(sWhj[m][k], sx[node][k], a);
            aj[(size_t)(jb + node) * GMD + m] = a;
        }
    }
}

// ---------------- readout + softmax ----------------
__global__ __launch_bounds__(1024)
void final_kernel(const float* __restrict__ h, const float* __restrict__ Wro,
                  const float* __restrict__ bro, float* __restrict__ out)
{
    __shared__ float slog[GN];
    __shared__ float sred[1024];
    __shared__ float swro[GSD];
    const int t = threadIdx.x;
    if (t < GSD) swro[t] = Wro[t];
    __syncthreads();
#pragma unroll
    for (int rr = 0; rr < 2; ++rr) {
        const int i = t + rr * 1024;
        float a = bro[0];
#pragma unroll
        for (int k = 0; k < GSD; ++k) a = fmaf(h[(size_t)i * GSD + k], swro[k], a);
        slog[i] = a;
    }
    __syncthreads();
    sred[t] = fmaxf(slog[t], slog[t + 1024]);
    __syncthreads();
    for (int s = 512; s > 0; s >>= 1) {
        if (t < s) sred[t] = fmaxf(sred[t], sred[t + s]);
        __syncthreads();
    }
    const float gmax = sred[0];
    __syncthreads();
    const float e0 = expf(slog[t] - gmax);
    const float e1 = expf(slog[t + 1024] - gmax);
    sred[t] = e0 + e1;
    __syncthreads();
    for (int s = 512; s > 0; s >>= 1) {
        if (t < s) sred[t] += sred[t + s];
        __syncthreads();
    }
    const float inv = 1.f / sred[0];
    out[t] = e0 * inv;
    out[t + 1024] = e1 * inv;
}

extern "C" void kernel_launch(void* const* d_in, const int* in_sizes, int n_in,
                              void* d_out, int out_size, void* d_ws, size_t ws_size,
                              hipStream_t stream)
{
    const float* J    = (const float*)d_in[0];
    const float* b    = (const float*)d_in[1];
    const float* Wmsg = (const float*)d_in[2];
    const float* bmsg = (const float*)d_in[3];
    const float* Wih  = (const float*)d_in[4];
    // d_in[5] = W_hh: unused by the reference math (only b_hh enters the gates)
    const float* bih  = (const float*)d_in[6];
    const float* bhh  = (const float*)d_in[7];
    const float* Wro  = (const float*)d_in[8];
    const float* bro  = (const float*)d_in[9];
    float* out = (float*)d_out;

    // workspace layout (floats); total ~17.6 MB
    float* ws    = (float*)d_ws;
    float* Jt    = ws;                            // N*N
    float* aiT0  = Jt   + (size_t)GN * GN;        // MD*N (transposed)
    float* aiT1  = aiT0 + (size_t)GN * GMD;       // MD*N (double buffer)
    float* ajb   = aiT1 + (size_t)GN * GMD;       // N*MD
    float* hbuf  = ajb  + (size_t)GN * GMD;       // N*SD
    float* msgb  = hbuf + (size_t)GN * GSD;       // N*MD

    transpose_kernel<<<dim3(32, 32), 256, 0, stream>>>(J, Jt);
    init_kernel<<<GN * GSD / 256, 256, 0, stream>>>(b, Wmsg, bmsg, aiT0, ajb, hbuf, msgb);

    float* ain = aiT0;
    float* aout = aiT1;
    for (int s = 0; s < GSTEPS; ++s) {
        step_kernel<<<NBLK, BLK, 0, stream>>>(Jt, ain, aout, ajb, hbuf, msgb,
                                              b, Wmsg, bmsg, Wih, bih, bhh);
        float* tmp = ain; ain = aout; aout = tmp;
    }
    final_kernel<<<1, 1024, 0, stream>>>(hbuf, Wro, bro, out);
}